// Round 4
// baseline (298.365 us; speedup 1.0000x reference)
//
#include <hip/hip_runtime.h>
#include <hip/hip_bf16.h>

typedef __bf16 bf16x4 __attribute__((ext_vector_type(4)));
typedef __bf16 bf16x8 __attribute__((ext_vector_type(8)));
typedef float  f32x4  __attribute__((ext_vector_type(4)));
typedef float  f32x16 __attribute__((ext_vector_type(16)));

#define MFMA32(a,b,c) __builtin_amdgcn_mfma_f32_32x32x16_bf16((a),(b),(c),0,0,0)

// Merged-weight TT forward (structure validated in R2; this round: W23 in
// registers, double-buffered Hb/Xt, 2 barriers/iter instead of 5).
//   W01[m0][(m1*8+r2)][(n0*8+n1)],  W23[(m2*8+m3)][(n2*32+n3*8+r2)]
// Per iter (2 batches): Xt[col=(b^,n2n3)][k=(n0,n1)]; per m0-quad q:
//   stage A: H = W01 @ Xt -> Hb[q][col=(b^,m0^,m1)][k=(n2,n3,r2)] (swizzled)
//   stage B: Y = W23 @ Hb[q], K=256, A-operand from VGPRs -> y + bias (NT)
// 32x32x16 layouts (HW-validated): A[m=lane&31][k=(lane>>5)*8+j], B[k][n=lane&31],
//   D[row=(reg&3)+8*(reg>>2)+4*(lane>>5)][col=lane&31].
// LDS map: [0,16384) w23 staging, reused as Hb[q=1]; [16384,32768) Hb[q=0];
//          [32768,36864) Xt double buffer. Total 72 KB -> 2 blocks/CU.

__global__ __launch_bounds__(256, 2) void tt_kernel(
    const float* __restrict__ x,  const float* __restrict__ c0,
    const float* __restrict__ c1, const float* __restrict__ c2,
    const float* __restrict__ c3, const float* __restrict__ bias,
    float* __restrict__ y)
{
    __shared__ __align__(16) __bf16 smem[36864];
    __bf16* w23l = smem;            // setup only, becomes hb1
    __bf16* hb1  = smem;
    __bf16* hb0  = smem + 16384;
    __bf16* xtb  = smem + 32768;    // 2 x 2048

    const int tid  = threadIdx.x;
    const int wid  = tid >> 6;
    const int lane = tid & 63;
    const int hh   = lane >> 5;
    const int c32  = lane & 31;
    const int rt   = wid & 1;       // row-tile role
    const int ct   = wid >> 1;      // batch role

    // ---- one-time: W23 -> LDS (swizzled: phys_oct = (k>>3) ^ (row&31)) ----
    {
      const int r = tid >> 2, kb = (tid & 3) * 64;
      const int m2 = r >> 3, m3 = r & 7;
      float c3v[8][4];
      #pragma unroll
      for (int r3 = 0; r3 < 8; ++r3)
        #pragma unroll
        for (int n3 = 0; n3 < 4; ++n3)
          c3v[r3][n3] = c3[(r3 * 8 + m3) * 4 + n3];
      for (int j = 0; j < 64; ++j) {
        const int k = kb + j;
        const int n2 = k >> 5, n3 = (k >> 3) & 3, r2 = k & 7;
        float s = 0.f;
        #pragma unroll
        for (int r3 = 0; r3 < 8; ++r3)
          s += c2[(r2 * 8 + m2) * 64 + r3 * 8 + n2] * c3v[r3][n3];
        w23l[r * 256 + (((k >> 3) ^ (r & 31)) << 3) + (k & 7)] = (__bf16)s;
      }
    }

    // ---- one-time: W01 A-frags (rt slice) in registers ----
    bf16x8 w01f[8][2];
    {
      const int row = rt * 32 + c32, m1 = row >> 3, r2w = row & 7;
      float c1row[8][8];
      #pragma unroll
      for (int r1 = 0; r1 < 8; ++r1)
        #pragma unroll
        for (int n1 = 0; n1 < 8; ++n1)
          c1row[r1][n1] = c1[(r1 * 8 + m1) * 64 + r2w * 8 + n1];
      for (int m0 = 0; m0 < 8; ++m0) {
        #pragma unroll
        for (int kt = 0; kt < 2; ++kt) {
          const int n0 = kt * 2 + hh;
          #pragma unroll
          for (int j = 0; j < 8; ++j) {
            float s = 0.f;
            #pragma unroll
            for (int r1 = 0; r1 < 8; ++r1)
              s += c0[m0 * 32 + r1 * 4 + n0] * c1row[r1][j];
            w01f[m0][kt][j] = (__bf16)s;
          }
        }
      }
    }
    __syncthreads();   // w23l built

    // ---- W23 A-frags (rt slice) -> registers ----
    bf16x8 w23f[16];
    {
      const __bf16* arow = &w23l[(rt * 32 + c32) * 256];
      #pragma unroll
      for (int kt = 0; kt < 16; ++kt)
        w23f[kt] = *(const bf16x8*)&arow[(((kt * 2 + hh) ^ c32) << 3)];
    }

    // ---- stage Xt[0] for iter 0 ----
    {
      const int bsel = tid >> 7, col = tid & 31, k0q = (tid >> 5) & 3;
      const float* xp = x + (size_t)(blockIdx.x * 16 + bsel) * 1024 + col;
      bf16x8 v;
      #pragma unroll
      for (int j = 0; j < 8; ++j) v[j] = (__bf16)xp[(k0q * 8 + j) * 32];
      *(bf16x8*)&xtb[(bsel * 32 + col) * 32 + ((k0q ^ (col & 3)) << 3)] = v;
    }
    __syncthreads();   // Xt[0] visible; all w23f reads done (hb1 safe to write)

    bf16x8 xf[2];
    #pragma unroll
    for (int kt = 0; kt < 2; ++kt)
      xf[kt] = *(const bf16x8*)
        &xtb[(ct * 32 + c32) * 32 + (((kt * 2 + hh) ^ (c32 & 3)) << 3)];

    for (int it = 0; it < 8; ++it) {
      const int b0 = (blockIdx.x * 8 + it) * 2;

      // ======== q = 0: stage A -> hb0 ========
      #pragma unroll
      for (int m0h = 0; m0h < 4; ++m0h) {
        f32x16 acc = {};
        acc = MFMA32(w01f[m0h][0], xf[0], acc);
        acc = MFMA32(w01f[m0h][1], xf[1], acc);
        #pragma unroll
        for (int p = 0; p < 4; ++p) {
          bf16x4 o;
          #pragma unroll
          for (int i = 0; i < 4; ++i) o[i] = (__bf16)acc[p * 4 + i];
          const int cl = ct * 32 + m0h * 8 + rt * 4 + p;
          *(bf16x4*)&hb0[cl * 256 + ((c32 ^ (cl & 31)) << 3) + hh * 4] = o;
        }
      }
      __syncthreads();   // barrier 1

      // ======== q = 0: stage B + epilogue ========
      {
        const __bf16* brow = &hb0[(ct * 32 + c32) * 256];
        f32x16 acc2 = {};
        #pragma unroll
        for (int kt = 0; kt < 16; ++kt)
          acc2 = MFMA32(w23f[kt],
                        *(const bf16x8*)&brow[(((kt * 2 + hh) ^ c32) << 3)],
                        acc2);
        const size_t ybase = (size_t)(b0 + ct) * 4096;
        const int boff = (c32 >> 3) * 512 + (c32 & 7) * 64 + hh * 4;
        #pragma unroll
        for (int p = 0; p < 4; ++p) {
          const int off = boff + (rt * 4 + p) * 8;
          const f32x4 bv = *(const f32x4*)&bias[off];
          f32x4 o;
          #pragma unroll
          for (int i = 0; i < 4; ++i) o[i] = acc2[p * 4 + i] + bv[i];
          __builtin_nontemporal_store(o, (f32x4*)&y[ybase + off]);
        }
      }

      // ======== q = 1: stage A -> hb1 ========
      #pragma unroll
      for (int m0h = 0; m0h < 4; ++m0h) {
        f32x16 acc = {};
        acc = MFMA32(w01f[4 + m0h][0], xf[0], acc);
        acc = MFMA32(w01f[4 + m0h][1], xf[1], acc);
        #pragma unroll
        for (int p = 0; p < 4; ++p) {
          bf16x4 o;
          #pragma unroll
          for (int i = 0; i < 4; ++i) o[i] = (__bf16)acc[p * 4 + i];
          const int cl = ct * 32 + m0h * 8 + rt * 4 + p;
          *(bf16x4*)&hb1[cl * 256 + ((c32 ^ (cl & 31)) << 3) + hh * 4] = o;
        }
      }
      // ---- prefetch next Xt (overlaps with q=1 stage A latency) ----
      if (it < 7) {
        const int bsel = tid >> 7, col = tid & 31, k0q = (tid >> 5) & 3;
        const float* xp = x + (size_t)(b0 + 2 + bsel) * 1024 + col;
        bf16x8 v;
        #pragma unroll
        for (int j = 0; j < 8; ++j) v[j] = (__bf16)xp[(k0q * 8 + j) * 32];
        *(bf16x8*)&xtb[((it + 1) & 1) * 2048 + (bsel * 32 + col) * 32 +
                       ((k0q ^ (col & 3)) << 3)] = v;
      }
      __syncthreads();   // barrier 2

      // ======== q = 1: stage B + epilogue ========
      {
        const __bf16* brow = &hb1[(ct * 32 + c32) * 256];
        f32x16 acc2 = {};
        #pragma unroll
        for (int kt = 0; kt < 16; ++kt)
          acc2 = MFMA32(w23f[kt],
                        *(const bf16x8*)&brow[(((kt * 2 + hh) ^ c32) << 3)],
                        acc2);
        const size_t ybase = (size_t)(b0 + ct) * 4096;
        const int boff = (4 + (c32 >> 3)) * 512 + (c32 & 7) * 64 + hh * 4;
        #pragma unroll
        for (int p = 0; p < 4; ++p) {
          const int off = boff + (rt * 4 + p) * 8;
          const f32x4 bv = *(const f32x4*)&bias[off];
          f32x4 o;
          #pragma unroll
          for (int i = 0; i < 4; ++i) o[i] = acc2[p * 4 + i] + bv[i];
          __builtin_nontemporal_store(o, (f32x4*)&y[ybase + off]);
        }
      }
      // ---- load next xf (xt[(it+1)&1] synced by barrier 2) ----
      if (it < 7) {
        const __bf16* xq = &xtb[((it + 1) & 1) * 2048];
        #pragma unroll
        for (int kt = 0; kt < 2; ++kt)
          xf[kt] = *(const bf16x8*)
            &xq[(ct * 32 + c32) * 32 + (((kt * 2 + hh) ^ (c32 & 3)) << 3)];
      }
    }
}

extern "C" void kernel_launch(void* const* d_in, const int* in_sizes, int n_in,
                              void* d_out, int out_size, void* d_ws, size_t ws_size,
                              hipStream_t stream) {
    const float* x    = (const float*)d_in[0];
    const float* c0   = (const float*)d_in[1];
    const float* c1   = (const float*)d_in[2];
    const float* c2   = (const float*)d_in[3];
    const float* c3   = (const float*)d_in[4];
    const float* bias = (const float*)d_in[5];
    float* yout = (float*)d_out;
    // persistent: 512 blocks (2/CU), 8 iters x 2 batches each
    tt_kernel<<<512, 256, 0, stream>>>(x, c0, c1, c2, c3, bias, yout);
}